// Round 1
// baseline (1138.445 us; speedup 1.0000x reference)
//
#include <hip/hip_runtime.h>
#include <math.h>

#define Bsz 512
#define Tt  2048
#define Hd  128
#define Ed  256
#define Vv  34

// d_out flat layout (floats)
#define OUT_OUT 0
#define OUT_C   17408
#define OUT_SH0 82944
#define OUT_SH1 148480
#define OUT_SC0 214016
#define OUT_SC1 279552
#define OUT_ATT 345088

__device__ __forceinline__ float sigm(float x) { return 1.0f / (1.0f + expf(-x)); }

// ---------------------------------------------------------------------------
// LSTM cell: gates = [x | h_prev] @ [W_ih | W_hh]^T + b_ih + b_hh
// One batch row per block, 512 threads: thread t computes gate t.
// 512 blocks -> 2 blocks/CU, 16 waves/CU (vs 4 before) for latency hiding.
// ---------------------------------------------------------------------------
template <int DXA, int DXB>
__global__ __launch_bounds__(512, 4) void lstm_cell_k(
    const float* __restrict__ xa, const float* __restrict__ xb,
    const float* __restrict__ hprev, const float* __restrict__ cprev,
    const float* __restrict__ W_ih, const float* __restrict__ W_hh,
    const float* __restrict__ b_ih, const float* __restrict__ b_hh,
    float* __restrict__ hout, float* __restrict__ cout)
{
    constexpr int DX = DXA + DXB;   // x dim (384 or 128)
    constexpr int XC = DX + Hd;     // x ++ h_prev
    __shared__ float xs[XC];
    __shared__ float gs[4 * Hd];

    const int b = blockIdx.x;
    const int tid = threadIdx.x;

    // stage x_cat for this row
    for (int i = tid; i < XC; i += 512) {
        float v;
        if (i < DXA)     v = xa[(size_t)b * DXA + i];
        else if (i < DX) v = xb[(size_t)b * DXB + (i - DXA)];
        else             v = hprev[(size_t)b * Hd + (i - DX)];
        xs[i] = v;
    }
    __syncthreads();

    // thread t: gate row t over [x | h]
    float ax = 0.f, ay = 0.f, az = 0.f, aw = 0.f;   // 4 independent chains
    {
        const float* w = W_ih + (size_t)tid * DX;
        for (int k = 0; k < DX; k += 4) {
            float4 a = *(const float4*)(w + k);
            float4 x = *(const float4*)(&xs[k]);       // LDS broadcast
            ax += a.x * x.x;
            ay += a.y * x.y;
            az += a.z * x.z;
            aw += a.w * x.w;
        }
    }
    {
        const float* u = W_hh + (size_t)tid * Hd;
        for (int k = 0; k < Hd; k += 4) {
            float4 a = *(const float4*)(u + k);
            float4 x = *(const float4*)(&xs[DX + k]);
            ax += a.x * x.x;
            ay += a.y * x.y;
            az += a.z * x.z;
            aw += a.w * x.w;
        }
    }
    gs[tid] = (ax + ay) + (az + aw) + b_ih[tid] + b_hh[tid];
    __syncthreads();

    // cell update: first 128 threads
    if (tid < Hd) {
        const int h = tid;
        const float ig = gs[h], fg = gs[Hd + h], gg = gs[2 * Hd + h], og = gs[3 * Hd + h];
        const float cp = cprev[(size_t)b * Hd + h];
        const float cn = sigm(fg) * cp + sigm(ig) * tanhf(gg);
        const float hn = sigm(og) * tanhf(cn);
        hout[(size_t)b * Hd + h] = hn;
        cout[(size_t)b * Hd + h] = cn;
    }
}

// ---------------------------------------------------------------------------
// Fused attention: scores = hk[b] @ sh1[b]; softmax*mask renorm; c = attn @ hv[b]
// One block of 1024 threads (16 waves) per batch element.
// Streaming loops unrolled x2 -> two outstanding 1KB wave-loads.
// ---------------------------------------------------------------------------
__global__ __launch_bounds__(1024, 8) void attn_k(
    const float* __restrict__ hk, const float* __restrict__ hv,
    const float* __restrict__ sh1, const float* __restrict__ mask,
    float* __restrict__ c_out, float* __restrict__ att_out)
{
    const int b = blockIdx.x;
    const int tid = threadIdx.x;
    const int w = tid >> 6;       // wave 0..15
    const int l = tid & 63;       // lane
    const int half = l >> 5;      // 0: row t, 1: row t+1
    const int l32 = l & 31;

    __shared__ float sc[Tt];
    __shared__ float ctx[16][Hd];
    __shared__ float red[16];
    __shared__ float bcast[2];

    const float* hkb = hk + (size_t)b * Tt * Hd;
    const float* hvb = hv + (size_t)b * Tt * Hd;

    const float4 s4 = *(const float4*)(sh1 + (size_t)b * Hd + l32 * 4);

    // ---- scores (unrolled x2: tp and tp+16) ----
    for (int tp = w; tp < Tt / 2; tp += 32) {
        const int t0 = tp * 2;
        const int t1 = t0 + 32;
        const float4 v0 = *(const float4*)(hkb + (size_t)t0 * Hd + l * 4);
        const float4 v1 = *(const float4*)(hkb + (size_t)t1 * Hd + l * 4);
        float p0 = v0.x * s4.x + v0.y * s4.y + v0.z * s4.z + v0.w * s4.w;
        float p1 = v1.x * s4.x + v1.y * s4.y + v1.z * s4.z + v1.w * s4.w;
        p0 += __shfl_xor(p0, 1);
        p1 += __shfl_xor(p1, 1);
        p0 += __shfl_xor(p0, 2);
        p1 += __shfl_xor(p1, 2);
        p0 += __shfl_xor(p0, 4);
        p1 += __shfl_xor(p1, 4);
        p0 += __shfl_xor(p0, 8);
        p1 += __shfl_xor(p1, 8);
        p0 += __shfl_xor(p0, 16);
        p1 += __shfl_xor(p1, 16);
        if (l32 == 0) {
            sc[t0 + half] = p0;
            sc[t1 + half] = p1;
        }
    }
    __syncthreads();

    // ---- softmax (max) ----
    float m = fmaxf(sc[tid], sc[tid + 1024]);
    for (int off = 1; off <= 32; off <<= 1) m = fmaxf(m, __shfl_xor(m, off));
    if (l == 0) red[w] = m;
    __syncthreads();
    if (tid == 0) {
        float mm = red[0];
        for (int i = 1; i < 16; i++) mm = fmaxf(mm, red[i]);
        bcast[0] = mm;
    }
    __syncthreads();
    const float M = bcast[0];

    // ---- exp * mask, sum ----
    const float* maskb = mask + (size_t)b * Tt;
    const float e0 = __expf(sc[tid] - M) * maskb[tid];
    const float e1 = __expf(sc[tid + 1024] - M) * maskb[tid + 1024];
    sc[tid] = e0;
    sc[tid + 1024] = e1;
    float s = e0 + e1;
    for (int off = 1; off <= 32; off <<= 1) s += __shfl_xor(s, off);
    if (l == 0) red[w] = s;
    __syncthreads();
    if (tid == 0) {
        float ss = 0.f;
        for (int i = 0; i < 16; i++) ss += red[i];
        bcast[1] = 1.0f / ss;
    }
    __syncthreads();
    const float inv = bcast[1];

    if (b == 0) {
        att_out[tid] = sc[tid] * inv;
        att_out[tid + 1024] = sc[tid + 1024] * inv;
    }

    // ---- context: c[h] = sum_t attn[t] * hv[b,t,h] (unrolled x2) ----
    float4 acc = {0.f, 0.f, 0.f, 0.f};
    for (int tp = w; tp < Tt / 2; tp += 32) {
        const int t0 = tp * 2;
        const int t1 = t0 + 32;
        const float a0 = sc[t0 + half] * inv;
        const float a1 = sc[t1 + half] * inv;
        const float4 v0 = *(const float4*)(hvb + (size_t)t0 * Hd + l * 4);
        const float4 v1 = *(const float4*)(hvb + (size_t)t1 * Hd + l * 4);
        acc.x += a0 * v0.x + a1 * v1.x;
        acc.y += a0 * v0.y + a1 * v1.y;
        acc.z += a0 * v0.z + a1 * v1.z;
        acc.w += a0 * v0.w + a1 * v1.w;
    }
    acc.x += __shfl_xor(acc.x, 32);
    acc.y += __shfl_xor(acc.y, 32);
    acc.z += __shfl_xor(acc.z, 32);
    acc.w += __shfl_xor(acc.w, 32);
    if (half == 0) *(float4*)(&ctx[w][l32 * 4]) = acc;
    __syncthreads();
    if (tid < Hd) {
        float v = 0.f;
        for (int i = 0; i < 16; i++) v += ctx[i][tid];
        c_out[(size_t)b * Hd + tid] = v;
    }
}

// ---------------------------------------------------------------------------
// Head part 1: pre = sh1@W1.T + b1 + c@W2.T + b2 ; accumulate column sum/sumsq
// ---------------------------------------------------------------------------
__device__ __forceinline__ float head_pre_dot(
    int h, const float* __restrict__ W1, const float* __restrict__ b1,
    const float* __restrict__ W2, const float* __restrict__ b2,
    const float* s1, const float* s2)
{
    const float* w1 = W1 + (size_t)h * Hd;
    const float* w2 = W2 + (size_t)h * Hd;
    float acc = b1[h] + b2[h];
    for (int k = 0; k < Hd; k += 4) {
        float4 a = *(const float4*)(w1 + k);
        float4 x = *(const float4*)(&s1[k]);
        acc += a.x * x.x + a.y * x.y + a.z * x.z + a.w * x.w;
        float4 bm = *(const float4*)(w2 + k);
        float4 y = *(const float4*)(&s2[k]);
        acc += bm.x * y.x + bm.y * y.y + bm.z * y.z + bm.w * y.w;
    }
    return acc;
}

__global__ __launch_bounds__(128) void head_sum_k(
    const float* __restrict__ sh1, const float* __restrict__ cvec,
    const float* __restrict__ W1, const float* __restrict__ b1,
    const float* __restrict__ W2, const float* __restrict__ b2,
    float* __restrict__ sum, float* __restrict__ sumsq)
{
    const int b = blockIdx.x;
    const int h = threadIdx.x;
    __shared__ float s1[Hd], s2[Hd];
    s1[h] = sh1[(size_t)b * Hd + h];
    s2[h] = cvec[(size_t)b * Hd + h];
    __syncthreads();
    const float acc = head_pre_dot(h, W1, b1, W2, b2, s1, s2);
    atomicAdd(&sum[h], acc);
    atomicAdd(&sumsq[h], acc * acc);
}

// ---------------------------------------------------------------------------
// Head part 2: recompute pre, BN(train)+ReLU, out = act@W3.T + b3
// ---------------------------------------------------------------------------
__global__ __launch_bounds__(128) void head_out_k(
    const float* __restrict__ sh1, const float* __restrict__ cvec,
    const float* __restrict__ W1, const float* __restrict__ b1,
    const float* __restrict__ W2, const float* __restrict__ b2,
    const float* __restrict__ sum, const float* __restrict__ sumsq,
    const float* __restrict__ gamma, const float* __restrict__ beta,
    const float* __restrict__ W3, const float* __restrict__ b3,
    float* __restrict__ out)
{
    const int b = blockIdx.x;
    const int h = threadIdx.x;
    __shared__ float s1[Hd], s2[Hd], act[Hd];
    s1[h] = sh1[(size_t)b * Hd + h];
    s2[h] = cvec[(size_t)b * Hd + h];
    __syncthreads();
    const float pre = head_pre_dot(h, W1, b1, W2, b2, s1, s2);
    const float mean = sum[h] * (1.0f / (float)Bsz);
    const float var = sumsq[h] * (1.0f / (float)Bsz) - mean * mean;
    const float a = (pre - mean) * rsqrtf(var + 1e-5f) * gamma[h] + beta[h];
    act[h] = fmaxf(a, 0.0f);
    __syncthreads();
    if (h < Vv) {
        const float* w3 = W3 + (size_t)h * Hd;
        float o = b3[h];
        for (int k = 0; k < Hd; k += 4) {
            float4 a4 = *(const float4*)(w3 + k);
            float4 x = *(const float4*)(&act[k]);
            o += a4.x * x.x + a4.y * x.y + a4.z * x.z + a4.w * x.w;
        }
        out[(size_t)b * Vv + h] = o;
    }
}

extern "C" void kernel_launch(void* const* d_in, const int* in_sizes, int n_in,
                              void* d_out, int out_size, void* d_ws, size_t ws_size,
                              hipStream_t stream)
{
    const float* hk    = (const float*)d_in[0];
    const float* hv    = (const float*)d_in[1];
    const float* y_1   = (const float*)d_in[2];
    const float* c_1   = (const float*)d_in[3];
    const float* sh_1  = (const float*)d_in[4];   // [2,B,H]
    const float* sc_1  = (const float*)d_in[5];   // [2,B,H]
    const float* mask  = (const float*)d_in[6];
    const float* W_ih0 = (const float*)d_in[7];
    const float* W_hh0 = (const float*)d_in[8];
    const float* b_ih0 = (const float*)d_in[9];
    const float* b_hh0 = (const float*)d_in[10];
    const float* W_ih1 = (const float*)d_in[11];
    const float* W_hh1 = (const float*)d_in[12];
    const float* b_ih1 = (const float*)d_in[13];
    const float* b_hh1 = (const float*)d_in[14];
    const float* W1    = (const float*)d_in[15];
    const float* b1    = (const float*)d_in[16];
    const float* W2    = (const float*)d_in[17];
    const float* b2    = (const float*)d_in[18];
    const float* W3    = (const float*)d_in[19];
    const float* b3    = (const float*)d_in[20];
    const float* gamma = (const float*)d_in[21];
    const float* beta  = (const float*)d_in[22];

    float* out = (float*)d_out;
    float* o_out = out + OUT_OUT;
    float* o_c   = out + OUT_C;
    float* o_sh0 = out + OUT_SH0;
    float* o_sh1 = out + OUT_SH1;
    float* o_sc0 = out + OUT_SC0;
    float* o_sc1 = out + OUT_SC1;
    float* o_att = out + OUT_ATT;

    float* ws_sum   = (float*)d_ws;        // 128 floats
    float* ws_sumsq = ws_sum + Hd;         // 128 floats
    hipMemsetAsync(d_ws, 0, 2 * Hd * sizeof(float), stream);

    // LSTM cell 0: x = [y_1 (256) | c_1 (128)]
    lstm_cell_k<Ed, Hd><<<Bsz, 512, 0, stream>>>(
        y_1, c_1, sh_1, sc_1, W_ih0, W_hh0, b_ih0, b_hh0, o_sh0, o_sc0);

    // LSTM cell 1: x = sh0 (128)
    lstm_cell_k<Hd, 0><<<Bsz, 512, 0, stream>>>(
        o_sh0, o_sh0, sh_1 + (size_t)Bsz * Hd, sc_1 + (size_t)Bsz * Hd,
        W_ih1, W_hh1, b_ih1, b_hh1, o_sh1, o_sc1);

    // fused attention + context
    attn_k<<<Bsz, 1024, 0, stream>>>(hk, hv, o_sh1, mask, o_c, o_att);

    // head
    head_sum_k<<<Bsz, 128, 0, stream>>>(o_sh1, o_c, W1, b1, W2, b2, ws_sum, ws_sumsq);
    head_out_k<<<Bsz, 128, 0, stream>>>(o_sh1, o_c, W1, b1, W2, b2, ws_sum, ws_sumsq,
                                        gamma, beta, W3, b3, o_out);
}